// Round 1
// baseline (518.649 us; speedup 1.0000x reference)
//
#include <hip/hip_runtime.h>
#include <hip/hip_bf16.h>

#define E_    8
#define CIN_  256
#define COUT_ 256
#define NK    9
#define KTOT  2304      // CIN*9
#define IMGH  56
#define IMGW  56
#define HW    3136
#define NBATCH 32

typedef __attribute__((ext_vector_type(8))) __bf16 bf16x8;
typedef __attribute__((ext_vector_type(4))) float f32x4;
typedef __attribute__((ext_vector_type(4))) unsigned int u32x4;

// ---------------- pooled[n][c] = mean_{h,w} x[n][c][h][w] ----------------
__global__ __launch_bounds__(256) void pool_kernel(const float* __restrict__ x,
                                                   float* __restrict__ pooled) {
    const int b = blockIdx.x;                 // n*CIN + c
    const float* xp = x + (size_t)b * HW;
    float s = 0.f;
    for (int i = threadIdx.x; i < HW; i += 256) s += xp[i];
    #pragma unroll
    for (int off = 32; off > 0; off >>= 1) s += __shfl_down(s, off, 64);
    __shared__ float red[4];
    if ((threadIdx.x & 63) == 0) red[threadIdx.x >> 6] = s;
    __syncthreads();
    if (threadIdx.x == 0)
        pooled[b] = (red[0] + red[1] + red[2] + red[3]) * (1.0f / HW);
}

// ---------------- gate[n][e] = sigmoid(pooled[n]·fc_w[e] + fc_b[e]) ------
__global__ __launch_bounds__(256) void gate_kernel(const float* __restrict__ pooled,
                                                   const float* __restrict__ fc_w,
                                                   const float* __restrict__ fc_b,
                                                   float* __restrict__ gate) {
    const int t = threadIdx.x;                // t = n*8 + e, 32*8 == 256
    const int n = t >> 3, e = t & 7;
    const float* pv = pooled + n * CIN_;
    const float* wv = fc_w + e * CIN_;
    float s = fc_b[e];
    for (int c = 0; c < CIN_; ++c) s += pv[c] * wv[c];
    gate[t] = 1.0f / (1.0f + expf(-s));
}

// ---- wmix[n][cout][khw*256+cin] = bf16( sum_e gate[n][e]*weight[e,cout,cin,khw] )
__global__ __launch_bounds__(256) void mix_kernel(const float* __restrict__ weight,
                                                  const float* __restrict__ gate,
                                                  __bf16* __restrict__ wmix) {
    const int b = blockIdx.x;                 // n*COUT + cout
    const int n = b >> 8;
    const int cout = b & 255;
    const int cin = threadIdx.x;
    float g[E_];
    #pragma unroll
    for (int e = 0; e < E_; ++e) g[e] = gate[n * E_ + e];
    float acc[NK];
    #pragma unroll
    for (int kk = 0; kk < NK; ++kk) acc[kk] = 0.f;
    #pragma unroll
    for (int e = 0; e < E_; ++e) {
        const float* wp = weight + (size_t)(e * COUT_ + cout) * KTOT + cin * NK;
        const float ge = g[e];
        #pragma unroll
        for (int kk = 0; kk < NK; ++kk) acc[kk] += ge * wp[kk];
    }
    __bf16* dst = wmix + (size_t)b * KTOT;
    #pragma unroll
    for (int kk = 0; kk < NK; ++kk) dst[kk * CIN_ + cin] = (__bf16)acc[kk];
}

// ---------------- implicit-GEMM conv, per-sample bf16 MFMA ----------------
// C tile: BM=128 couts x BN=64 pixels, BK=64 over K=2304 (khw-major).
#define BM 128
#define BN 64
#define LDK 72   // 64 + 8 pad: rows 144B -> 16B-aligned b128, ~2-way banks

__global__ __launch_bounds__(256) void conv_kernel(const float* __restrict__ x,
                                                   const __bf16* __restrict__ wmix,
                                                   float* __restrict__ out) {
    __shared__ __attribute__((aligned(16))) __bf16 At[BM][LDK];  // [cout][k]
    __shared__ __attribute__((aligned(16))) __bf16 Bt[BN][LDK];  // [pixel][k]

    const int tid  = threadIdx.x;
    const int lane = tid & 63;
    const int wave = tid >> 6;
    const int p0    = blockIdx.x * BN;       // 49 pixel tiles (49*64==3136)
    const int cout0 = blockIdx.y * BM;       // 2 cout tiles
    const int n     = blockIdx.z;            // 32 samples

    // B staging: thread -> pixel pl, k rows klb..klb+15
    const int pl  = tid & 63;
    const int klb = (tid >> 6) * 16;
    const int p = p0 + pl;
    const int h = p / IMGW;
    const int w = p - h * IMGW;
    const float* xn = x + (size_t)n * CIN_ * HW;

    // A staging: thread -> row ar, 32-bf16 half ah
    const int ar = tid >> 1;
    const int ah = (tid & 1) * 32;
    const __bf16* wrow = wmix + (size_t)(n * COUT_ + cout0 + ar) * KTOT;

    const f32x4 zero = {0.f, 0.f, 0.f, 0.f};
    f32x4 acc[2][4];
    #pragma unroll
    for (int i = 0; i < 2; ++i)
        #pragma unroll
        for (int j = 0; j < 4; ++j) acc[i][j] = zero;

    const int m0 = wave * 32;                // wave's 32 cout rows
    const int fr = lane & 15;                // M/N index within fragment
    const int kq = (lane >> 4) * 8;          // K-group offset

    for (int khw = 0; khw < NK; ++khw) {
        const int kh = khw / 3;
        const int kw = khw - kh * 3;
        const int hh = h + kh - 1;
        const int ww = w + kw - 1;
        const bool valid = (hh >= 0) && (hh < IMGH) && (ww >= 0) && (ww < IMGW);
        const float* xpix = xn + (size_t)klb * HW + (hh * IMGW + ww);

        for (int cb = 0; cb < 4; ++cb) {
            const int k0 = khw * 256 + cb * 64;
            // ---- stage A (weights, bf16, contiguous) ----
            {
                const __bf16* src = wrow + k0 + ah;
                u32x4 v0 = *(const u32x4*)(src);
                u32x4 v1 = *(const u32x4*)(src + 8);
                u32x4 v2 = *(const u32x4*)(src + 16);
                u32x4 v3 = *(const u32x4*)(src + 24);
                *(u32x4*)&At[ar][ah]      = v0;
                *(u32x4*)&At[ar][ah + 8]  = v1;
                *(u32x4*)&At[ar][ah + 16] = v2;
                *(u32x4*)&At[ar][ah + 24] = v3;
            }
            // ---- stage B (x gather, fp32 -> bf16; zero for pad) ----
            {
                const float* xb = xpix + (size_t)(cb * 64) * HW;
                bf16x8 v0, v1;
                #pragma unroll
                for (int jj = 0; jj < 8; ++jj) {
                    float f0 = 0.f, f1 = 0.f;
                    if (valid) {
                        f0 = xb[(size_t)jj * HW];
                        f1 = xb[(size_t)(jj + 8) * HW];
                    }
                    v0[jj] = (__bf16)f0;
                    v1[jj] = (__bf16)f1;
                }
                *(bf16x8*)&Bt[pl][klb]     = v0;
                *(bf16x8*)&Bt[pl][klb + 8] = v1;
            }
            __syncthreads();
            // ---- MFMA: 2 k-slices of 32, 2x4 fragments ----
            #pragma unroll
            for (int ks = 0; ks < 2; ++ks) {
                const int kb = ks * 32 + kq;
                bf16x8 a0 = *(const bf16x8*)&At[m0 + fr][kb];
                bf16x8 a1 = *(const bf16x8*)&At[m0 + 16 + fr][kb];
                bf16x8 b0 = *(const bf16x8*)&Bt[fr][kb];
                bf16x8 b1 = *(const bf16x8*)&Bt[16 + fr][kb];
                bf16x8 b2 = *(const bf16x8*)&Bt[32 + fr][kb];
                bf16x8 b3 = *(const bf16x8*)&Bt[48 + fr][kb];
                acc[0][0] = __builtin_amdgcn_mfma_f32_16x16x32_bf16(a0, b0, acc[0][0], 0, 0, 0);
                acc[0][1] = __builtin_amdgcn_mfma_f32_16x16x32_bf16(a0, b1, acc[0][1], 0, 0, 0);
                acc[0][2] = __builtin_amdgcn_mfma_f32_16x16x32_bf16(a0, b2, acc[0][2], 0, 0, 0);
                acc[0][3] = __builtin_amdgcn_mfma_f32_16x16x32_bf16(a0, b3, acc[0][3], 0, 0, 0);
                acc[1][0] = __builtin_amdgcn_mfma_f32_16x16x32_bf16(a1, b0, acc[1][0], 0, 0, 0);
                acc[1][1] = __builtin_amdgcn_mfma_f32_16x16x32_bf16(a1, b1, acc[1][1], 0, 0, 0);
                acc[1][2] = __builtin_amdgcn_mfma_f32_16x16x32_bf16(a1, b2, acc[1][2], 0, 0, 0);
                acc[1][3] = __builtin_amdgcn_mfma_f32_16x16x32_bf16(a1, b3, acc[1][3], 0, 0, 0);
            }
            __syncthreads();
        }
    }

    // epilogue: D layout col = lane&15 (pixel), row = (lane>>4)*4 + reg (cout)
    const int rbase = (lane >> 4) * 4;
    float* outn = out + (size_t)(n * COUT_ + cout0 + m0) * HW + p0;
    #pragma unroll
    for (int fm = 0; fm < 2; ++fm)
        #pragma unroll
        for (int fn = 0; fn < 4; ++fn)
            #pragma unroll
            for (int r = 0; r < 4; ++r)
                outn[(size_t)(fm * 16 + rbase + r) * HW + fn * 16 + fr] = acc[fm][fn][r];
}

extern "C" void kernel_launch(void* const* d_in, const int* in_sizes, int n_in,
                              void* d_out, int out_size, void* d_ws, size_t ws_size,
                              hipStream_t stream) {
    const float* x      = (const float*)d_in[0];
    const float* weight = (const float*)d_in[1];
    const float* fc_w   = (const float*)d_in[2];
    const float* fc_b   = (const float*)d_in[3];
    float* out = (float*)d_out;

    // workspace layout (needs ~37.8 MB)
    float* pooled = (float*)d_ws;                     // 8192 f32
    float* gate   = pooled + NBATCH * CIN_;           // 256 f32
    __bf16* wmix  = (__bf16*)(gate + NBATCH * E_);    // 32*256*2304 bf16 = 37.75 MB

    pool_kernel<<<dim3(NBATCH * CIN_), 256, 0, stream>>>(x, pooled);
    gate_kernel<<<dim3(1), 256, 0, stream>>>(pooled, fc_w, fc_b, gate);
    mix_kernel<<<dim3(NBATCH * COUT_), 256, 0, stream>>>(weight, gate, wmix);
    conv_kernel<<<dim3(49, 2, NBATCH), 256, 0, stream>>>(x, wmix, out);
}

// Round 3
// 299.772 us; speedup vs baseline: 1.7301x; 1.7301x over previous
//
#include <hip/hip_runtime.h>
#include <hip/hip_bf16.h>

#define E_    8
#define CIN_  256
#define COUT_ 256
#define NK    9
#define KTOT  2304      // CIN*9
#define IMGH  56
#define IMGW  56
#define HW    3136
#define NBATCH 32

typedef __attribute__((ext_vector_type(8))) __bf16 bf16x8;
typedef __attribute__((ext_vector_type(4))) float f32x4;
typedef __attribute__((ext_vector_type(4))) unsigned int u32x4;

// ---------------- pooled[n][c] = mean_{h,w} x[n][c][h][w] ----------------
__global__ __launch_bounds__(256) void pool_kernel(const float* __restrict__ x,
                                                   float* __restrict__ pooled) {
    const int b = blockIdx.x;                 // n*CIN + c
    const float* xp = x + (size_t)b * HW;
    float s = 0.f;
    for (int i = threadIdx.x; i < HW; i += 256) s += xp[i];
    #pragma unroll
    for (int off = 32; off > 0; off >>= 1) s += __shfl_down(s, off, 64);
    __shared__ float red[4];
    if ((threadIdx.x & 63) == 0) red[threadIdx.x >> 6] = s;
    __syncthreads();
    if (threadIdx.x == 0)
        pooled[b] = (red[0] + red[1] + red[2] + red[3]) * (1.0f / HW);
}

// ---------------- gate[n][e] = sigmoid(pooled[n]·fc_w[e] + fc_b[e]) ------
__global__ __launch_bounds__(256) void gate_kernel(const float* __restrict__ pooled,
                                                   const float* __restrict__ fc_w,
                                                   const float* __restrict__ fc_b,
                                                   float* __restrict__ gate) {
    const int t = threadIdx.x;                // t = n*8 + e, 32*8 == 256
    const int n = t >> 3, e = t & 7;
    const float* pv = pooled + n * CIN_;
    const float* wv = fc_w + e * CIN_;
    float s = fc_b[e];
    for (int c = 0; c < CIN_; ++c) s += pv[c] * wv[c];
    gate[t] = 1.0f / (1.0f + expf(-s));
}

// ---- wmix[n][cout][khw*256+cin] = bf16( sum_e gate[n][e]*weight[e,cout,cin,khw] )
__global__ __launch_bounds__(256) void mix_kernel(const float* __restrict__ weight,
                                                  const float* __restrict__ gate,
                                                  __bf16* __restrict__ wmix) {
    const int b = blockIdx.x;                 // n*COUT + cout
    const int n = b >> 8;
    const int cout = b & 255;
    const int cin = threadIdx.x;
    float g[E_];
    #pragma unroll
    for (int e = 0; e < E_; ++e) g[e] = gate[n * E_ + e];
    float acc[NK];
    #pragma unroll
    for (int kk = 0; kk < NK; ++kk) acc[kk] = 0.f;
    #pragma unroll
    for (int e = 0; e < E_; ++e) {
        const float* wp = weight + (size_t)(e * COUT_ + cout) * KTOT + cin * NK;
        const float ge = g[e];
        #pragma unroll
        for (int kk = 0; kk < NK; ++kk) acc[kk] += ge * wp[kk];
    }
    __bf16* dst = wmix + (size_t)b * KTOT;
    #pragma unroll
    for (int kk = 0; kk < NK; ++kk) dst[kk * CIN_ + cin] = (__bf16)acc[kk];
}

// ---- xT[n][px][cin] = bf16(x[n][cin][px]) : one-time transpose ----------
__global__ __launch_bounds__(256) void transpose_kernel(const float* __restrict__ x,
                                                        __bf16* __restrict__ xT) {
    __shared__ __bf16 t[64][66];              // +2 pad: read stride 132B -> 2-way banks
    const int px0 = blockIdx.x * 64;
    const int c0  = blockIdx.y * 64;
    const int n   = blockIdx.z;
    const int tid = threadIdx.x;
    // read: lanes -> px (coalesced 256B)
    {
        const int px_l = tid & 63;
        const int cb   = (tid >> 6) * 16;
        #pragma unroll
        for (int i = 0; i < 16; ++i) {
            const int cin_l = cb + i;
            t[cin_l][px_l] =
                (__bf16)x[((size_t)(n * CIN_ + c0 + cin_l)) * HW + px0 + px_l];
        }
    }
    __syncthreads();
    // write: lanes -> cin (coalesced 128B)
    {
        const int cin_l = tid & 63;
        const int pb    = (tid >> 6) * 16;
        #pragma unroll
        for (int i = 0; i < 16; ++i) {
            const int px_l = pb + i;
            xT[((size_t)(n * HW + px0 + px_l)) * CIN_ + c0 + cin_l] = t[cin_l][px_l];
        }
    }
}

// ---------------- implicit-GEMM conv, per-sample bf16 MFMA ----------------
// C tile: BM=128 couts x BN=64 pixels, BK=64 over K=2304 (tap-major).
// LDS layout (both tiles): row-major [row][64], 16B slots XOR-swizzled:
//   elem(row, cin) at  row*64 + ((cin>>3) ^ (row&7))*8 + (cin&7)
#define BM 128
#define BN 64

__global__ __launch_bounds__(256) void conv_kernel(const __bf16* __restrict__ xT,
                                                   const __bf16* __restrict__ wmix,
                                                   float* __restrict__ out) {
    __shared__ __attribute__((aligned(16))) __bf16 At[BM * 64];  // 16 KB
    __shared__ __attribute__((aligned(16))) __bf16 Bt[BN * 64];  //  8 KB

    const int tid  = threadIdx.x;
    const int lane = tid & 63;
    const int wave = tid >> 6;
    const int p0    = blockIdx.x * BN;        // 49 pixel tiles
    const int cout0 = blockIdx.y * BM;        // 2 cout tiles
    const int n     = blockIdx.z;             // 32 samples

    // A staging: thread -> cout row, 4 consecutive 16B slots (32 cins)
    const int acout = tid >> 1;
    const int as0   = (tid & 1) * 4;
    const __bf16* wrow = wmix + (size_t)(n * COUT_ + cout0 + acout) * KTOT;
    const int aswz = acout & 7;

    // B staging: thread -> pixel, 2 consecutive 16B slots (16 cins)
    const int bpx = tid >> 2;
    const int bs0 = (tid & 3) * 2;
    const int px  = p0 + bpx;
    const int ph  = px / IMGW;
    const int pw  = px - ph * IMGW;
    const __bf16* xTn = xT + (size_t)n * HW * CIN_;
    const int bswz = bpx & 7;

    const f32x4 zero = {0.f, 0.f, 0.f, 0.f};
    f32x4 acc[2][4];
    #pragma unroll
    for (int i = 0; i < 2; ++i)
        #pragma unroll
        for (int j = 0; j < 4; ++j) acc[i][j] = zero;

    const int m0 = wave * 32;                 // wave's 32 cout rows
    const int fr = lane & 15;
    const int kg = lane >> 4;                 // K-group 0..3
    const int fswz = fr & 7;

    for (int khw = 0; khw < NK; ++khw) {
        const int kh = khw / 3;
        const int kw = khw - kh * 3;
        const int hh = ph + kh - 1;
        const int ww = pw + kw - 1;
        const bool valid = (hh >= 0) && (hh < IMGH) && (ww >= 0) && (ww < IMGW);
        const __bf16* bsrc0 = xTn + (size_t)(hh * IMGW + ww) * CIN_;

        for (int cb = 0; cb < 4; ++cb) {
            // ---- stage A: 64B contiguous read, 4 swizzled 16B LDS writes ----
            {
                const __bf16* src = wrow + khw * 256 + cb * 64 + as0 * 8;
                u32x4 v0 = *(const u32x4*)(src);
                u32x4 v1 = *(const u32x4*)(src + 8);
                u32x4 v2 = *(const u32x4*)(src + 16);
                u32x4 v3 = *(const u32x4*)(src + 24);
                __bf16* dst = At + acout * 64;
                *(u32x4*)(dst + ((as0 + 0) ^ aswz) * 8) = v0;
                *(u32x4*)(dst + ((as0 + 1) ^ aswz) * 8) = v1;
                *(u32x4*)(dst + ((as0 + 2) ^ aswz) * 8) = v2;
                *(u32x4*)(dst + ((as0 + 3) ^ aswz) * 8) = v3;
            }
            // ---- stage B: 32B contiguous read (zero if pad), 2 swizzled writes ----
            {
                u32x4 v0 = {0u, 0u, 0u, 0u}, v1 = {0u, 0u, 0u, 0u};
                if (valid) {
                    const __bf16* src = bsrc0 + cb * 64 + bs0 * 8;
                    v0 = *(const u32x4*)(src);
                    v1 = *(const u32x4*)(src + 8);
                }
                __bf16* dst = Bt + bpx * 64;
                *(u32x4*)(dst + ((bs0 + 0) ^ bswz) * 8) = v0;
                *(u32x4*)(dst + ((bs0 + 1) ^ bswz) * 8) = v1;
            }
            __syncthreads();
            // ---- MFMA: 2 k-slices of 32, 2x4 fragments ----
            #pragma unroll
            for (int ks = 0; ks < 2; ++ks) {
                const int slot = ks * 4 + kg;
                const int soff = (slot ^ fswz) * 8;
                bf16x8 a0 = *(const bf16x8*)(At + (m0 + fr) * 64 + soff);
                bf16x8 a1 = *(const bf16x8*)(At + (m0 + 16 + fr) * 64 + soff);
                bf16x8 b0 = *(const bf16x8*)(Bt + (fr) * 64 + soff);
                bf16x8 b1 = *(const bf16x8*)(Bt + (16 + fr) * 64 + soff);
                bf16x8 b2 = *(const bf16x8*)(Bt + (32 + fr) * 64 + soff);
                bf16x8 b3 = *(const bf16x8*)(Bt + (48 + fr) * 64 + soff);
                acc[0][0] = __builtin_amdgcn_mfma_f32_16x16x32_bf16(a0, b0, acc[0][0], 0, 0, 0);
                acc[0][1] = __builtin_amdgcn_mfma_f32_16x16x32_bf16(a0, b1, acc[0][1], 0, 0, 0);
                acc[0][2] = __builtin_amdgcn_mfma_f32_16x16x32_bf16(a0, b2, acc[0][2], 0, 0, 0);
                acc[0][3] = __builtin_amdgcn_mfma_f32_16x16x32_bf16(a0, b3, acc[0][3], 0, 0, 0);
                acc[1][0] = __builtin_amdgcn_mfma_f32_16x16x32_bf16(a1, b0, acc[1][0], 0, 0, 0);
                acc[1][1] = __builtin_amdgcn_mfma_f32_16x16x32_bf16(a1, b1, acc[1][1], 0, 0, 0);
                acc[1][2] = __builtin_amdgcn_mfma_f32_16x16x32_bf16(a1, b2, acc[1][2], 0, 0, 0);
                acc[1][3] = __builtin_amdgcn_mfma_f32_16x16x32_bf16(a1, b3, acc[1][3], 0, 0, 0);
            }
            __syncthreads();
        }
    }

    // epilogue: D layout col = lane&15 (pixel), row = (lane>>4)*4 + reg (cout)
    const int rbase = (lane >> 4) * 4;
    float* outn = out + (size_t)(n * COUT_ + cout0 + m0) * HW + p0;
    #pragma unroll
    for (int fm = 0; fm < 2; ++fm)
        #pragma unroll
        for (int fn = 0; fn < 4; ++fn)
            #pragma unroll
            for (int r = 0; r < 4; ++r)
                outn[(size_t)(fm * 16 + rbase + r) * HW + fn * 16 + fr] = acc[fm][fn][r];
}

extern "C" void kernel_launch(void* const* d_in, const int* in_sizes, int n_in,
                              void* d_out, int out_size, void* d_ws, size_t ws_size,
                              hipStream_t stream) {
    const float* x      = (const float*)d_in[0];
    const float* weight = (const float*)d_in[1];
    const float* fc_w   = (const float*)d_in[2];
    const float* fc_b   = (const float*)d_in[3];
    float* out = (float*)d_out;

    // workspace layout (~89.2 MB)
    char* ws = (char*)d_ws;
    float* pooled = (float*)ws;                                   // 32 KB
    float* gate   = (float*)(ws + 64 * 1024 - 4096);              // 1 KB region
    __bf16* wmix  = (__bf16*)(ws + 64 * 1024);                    // 37.75 MB
    __bf16* xT    = (__bf16*)(ws + 64 * 1024 + (size_t)NBATCH * COUT_ * KTOT * 2);

    pool_kernel<<<dim3(NBATCH * CIN_), 256, 0, stream>>>(x, pooled);
    gate_kernel<<<dim3(1), 256, 0, stream>>>(pooled, fc_w, fc_b, gate);
    mix_kernel<<<dim3(NBATCH * COUT_), 256, 0, stream>>>(weight, gate, wmix);
    transpose_kernel<<<dim3(49, 4, NBATCH), 256, 0, stream>>>(x, xT);
    conv_kernel<<<dim3(49, 2, NBATCH), 256, 0, stream>>>(xT, wmix, out);
}

// Round 4
// 252.602 us; speedup vs baseline: 2.0532x; 1.1867x over previous
//
#include <hip/hip_runtime.h>
#include <hip/hip_bf16.h>

#define E_    8
#define CIN_  256
#define COUT_ 256
#define NK    9
#define KTOT  2304      // CIN*9
#define IMGH  56
#define IMGW  56
#define HW    3136
#define NBATCH 32
#define PADW  58
#define PADHW 3364      // 58*58

typedef __attribute__((ext_vector_type(8))) __bf16 bf16x8;
typedef __attribute__((ext_vector_type(4))) float f32x4;
typedef unsigned int u32;

// async global->LDS, 16B per lane; LDS dest = wave-uniform base + lane*16
__device__ __forceinline__ void gld_lds16(const __bf16* g, __bf16* l) {
    __builtin_amdgcn_global_load_lds(
        (const __attribute__((address_space(1))) void*)(g),
        (__attribute__((address_space(3))) void*)(l), 16, 0, 0);
}

// ---- halo zero: xTp borders = 0 (re-zeroed every call; ws not re-poisoned but
//      first call after poison must see zeros) ----
__global__ __launch_bounds__(256) void halo_zero_kernel(__bf16* xTp) {
    const int total = NBATCH * 228 * 128;     // u32 count (halo px * 128 u32/row)
    u32* p = (u32*)xTp;
    for (int idx = blockIdx.x * 256 + threadIdx.x; idx < total; idx += gridDim.x * 256) {
        const int n  = idx / (228 * 128);
        const int r  = idx - n * (228 * 128);
        const int hp = r >> 7;                // halo px index 0..227
        const int cp = r & 127;               // u32 within cin row
        int px;
        if (hp < 58)       px = hp;                         // top row
        else if (hp < 116) px = 57 * PADW + (hp - 58);      // bottom row
        else if (hp < 172) px = (hp - 116 + 1) * PADW;      // left col
        else               px = (hp - 172 + 1) * PADW + 57; // right col
        p[((size_t)(n * PADHW + px)) * 128 + cp] = 0u;
    }
}

// ---- transpose + pool: xTp[n][(h+1)*58+(w+1)][cin] = bf16(x[n][cin][h][w]),
//      pooled[n][c] += partial channel sums (atomic) ----
__global__ __launch_bounds__(256) void transpose_kernel(const float* __restrict__ x,
                                                        __bf16* __restrict__ xTp,
                                                        float* __restrict__ pooled) {
    __shared__ __bf16 t[64][66];
    const int px0 = blockIdx.x * 64;
    const int c0  = blockIdx.y * 64;
    const int n   = blockIdx.z;
    const int tid = threadIdx.x;
    {   // read: lanes -> px (coalesced 256B rows)
        const int px_l = tid & 63;
        const int cb   = (tid >> 6) * 16;
        #pragma unroll
        for (int i = 0; i < 16; ++i) {
            const int cin_l = cb + i;
            t[cin_l][px_l] =
                (__bf16)x[((size_t)(n * CIN_ + c0 + cin_l)) * HW + px0 + px_l];
        }
    }
    __syncthreads();
    {   // write: lanes -> cin (coalesced), plus per-cin partial pool sum
        const int cin_l = tid & 63;
        const int pb    = (tid >> 6) * 16;
        float s = 0.f;
        #pragma unroll
        for (int i = 0; i < 16; ++i) {
            const int px = px0 + pb + i;
            const int h  = px / IMGW;
            const int w  = px - h * IMGW;
            const __bf16 v = t[cin_l][pb + i];
            s += (float)v;
            xTp[((size_t)(n * PADHW + (h + 1) * PADW + (w + 1))) * CIN_ + c0 + cin_l] = v;
        }
        atomicAdd(&pooled[n * CIN_ + c0 + cin_l], s);
    }
}

// ---- gate[n][e] = sigmoid(pooledsum[n]/HW . fc_w[e] + fc_b[e]) ----------
__global__ __launch_bounds__(256) void gate_kernel(const float* __restrict__ pooled,
                                                   const float* __restrict__ fc_w,
                                                   const float* __restrict__ fc_b,
                                                   float* __restrict__ gate) {
    const int t = threadIdx.x;                // t = n*8 + e
    const int n = t >> 3, e = t & 7;
    const float* pv = pooled + n * CIN_;
    const float* wv = fc_w + e * CIN_;
    float s = 0.f;
    for (int c = 0; c < CIN_; ++c) s += pv[c] * wv[c];
    s = s * (1.0f / HW) + fc_b[e];
    gate[t] = 1.0f / (1.0f + expf(-s));
}

// ---- wmix[n][cout][kk*256+cin] = bf16(sum_e g*W), coalesced via flat index +
//      LDS transpose ----
__global__ __launch_bounds__(256) void mix_kernel(const float* __restrict__ weight,
                                                  const float* __restrict__ gate,
                                                  __bf16* __restrict__ wmix) {
    __shared__ __bf16 lds[KTOT];
    const int b = blockIdx.x;                 // n*COUT + cout
    const int n = b >> 8;
    const int cout = b & 255;
    const int tid = threadIdx.x;
    float g[E_];
    #pragma unroll
    for (int e = 0; e < E_; ++e) g[e] = gate[n * E_ + e];
    float acc[NK];
    #pragma unroll
    for (int i = 0; i < NK; ++i) acc[i] = 0.f;
    #pragma unroll
    for (int e = 0; e < E_; ++e) {
        const float* wp = weight + (size_t)(e * COUT_ + cout) * KTOT;
        const float ge = g[e];
        #pragma unroll
        for (int i = 0; i < NK; ++i) acc[i] += ge * wp[tid + i * 256];
    }
    #pragma unroll
    for (int i = 0; i < NK; ++i) {
        const int kf  = tid + i * 256;        // = cin*9 + kk
        const int cin = (kf * 7282) >> 16;    // kf/9 exact for kf<2304
        const int kk  = kf - cin * 9;
        lds[kk * 256 + cin] = (__bf16)acc[i];
    }
    __syncthreads();
    u32* dst = (u32*)(wmix + (size_t)b * KTOT);
    const u32* src = (const u32*)lds;
    #pragma unroll
    for (int j = 0; j < 4; ++j) dst[tid + j * 256] = src[tid + j * 256];
    if (tid < 128) dst[tid + 1024] = src[tid + 1024];
}

// ---------------- implicit-GEMM conv: 2-phase global_load_lds pipeline ----
// BM=128 couts x BN=64 pixels, 36 K-steps of 64 (tap-major, padded image).
// LDS content at (row, slot s) = global slot s ^ (row&7); source pre-swizzled.
#define BM 128
#define BN 64

__global__ __launch_bounds__(256) void conv_kernel(const __bf16* __restrict__ xTp,
                                                   const __bf16* __restrict__ wmix,
                                                   float* __restrict__ out) {
    __shared__ __attribute__((aligned(16))) __bf16 At[2][BM * 64];  // 2x16 KB
    __shared__ __attribute__((aligned(16))) __bf16 Bt[2][BN * 64];  // 2x 8 KB

    // bijective XCD swizzle (3136 % 8 == 0)
    const int bid = blockIdx.x;
    const int swz = (bid & 7) * 392 + (bid >> 3);
    const int pt  = swz % 49;
    const int rem = swz / 49;
    const int ct  = rem & 1;
    const int n   = rem >> 1;
    const int p0    = pt * BN;
    const int cout0 = ct * BM;

    const int tid  = threadIdx.x;
    const int lane = tid & 63;
    const int wave = tid >> 6;
    const int lr   = lane >> 3;               // row-within-chunk 0..7
    const int sl   = lane & 7;                // 16B slot within 128B row
    const int swzsl = sl ^ lr;                // pre-swizzled source slot

    // A staging: 4 chunks/thread; row rA = (wave+4i)*8 + lr
    const __bf16* wmixn = wmix + (size_t)n * COUT_ * KTOT;
    const __bf16* asrc[4];
    #pragma unroll
    for (int i = 0; i < 4; ++i) {
        const int rA = (wave + 4 * i) * 8 + lr;
        asrc[i] = wmixn + (size_t)(cout0 + rA) * KTOT + swzsl * 8;
    }
    // B staging: 2 chunks/thread; rows rB0, rB0+32
    const int rB0 = wave * 8 + lr;
    const int pB0 = p0 + rB0;
    const int pB1 = p0 + rB0 + 32;
    const int h0 = pB0 / IMGW, w0 = pB0 - (pB0 / IMGW) * IMGW;
    const int h1 = pB1 / IMGW, w1 = pB1 - (pB1 / IMGW) * IMGW;
    const __bf16* xTpn = xTp + (size_t)n * PADHW * CIN_;

    const f32x4 zero = {0.f, 0.f, 0.f, 0.f};
    f32x4 acc[2][4];
    #pragma unroll
    for (int i = 0; i < 2; ++i)
        #pragma unroll
        for (int j = 0; j < 4; ++j) acc[i][j] = zero;

    const int m0 = wave * 32;
    const int fr = lane & 15;
    const int kg = lane >> 4;
    const int fswz = fr & 7;

    auto STAGE = [&](int buf, int step) {
        const int cb  = step & 3;
        const int khw = step >> 2;
        const int kh  = (khw * 11) >> 5;      // khw/3 for khw<9
        const int kw  = khw - kh * 3;
        #pragma unroll
        for (int i = 0; i < 4; ++i)
            gld_lds16(asrc[i] + step * 64, &At[buf][(wave + 4 * i) * 512]);
        const int boff = cb * 64 + swzsl * 8;
        gld_lds16(xTpn + (size_t)((h0 + kh) * PADW + (w0 + kw)) * CIN_ + boff,
                  &Bt[buf][wave * 512]);
        gld_lds16(xTpn + (size_t)((h1 + kh) * PADW + (w1 + kw)) * CIN_ + boff,
                  &Bt[buf][(wave + 4) * 512]);
    };

    STAGE(0, 0);
    __syncthreads();                          // drains vmcnt(0)
    int buf = 0;
    for (int step = 0; step < 36; ++step) {
        if (step < 35) STAGE(buf ^ 1, step + 1);
        const __bf16* Ab = &At[buf][0];
        const __bf16* Bb = &Bt[buf][0];
        #pragma unroll
        for (int ks = 0; ks < 2; ++ks) {
            const int soff = ((ks * 4 + kg) ^ fswz) * 8;
            bf16x8 a0 = *(const bf16x8*)(Ab + (m0 + fr) * 64 + soff);
            bf16x8 a1 = *(const bf16x8*)(Ab + (m0 + 16 + fr) * 64 + soff);
            bf16x8 b0 = *(const bf16x8*)(Bb + (fr) * 64 + soff);
            bf16x8 b1 = *(const bf16x8*)(Bb + (16 + fr) * 64 + soff);
            bf16x8 b2 = *(const bf16x8*)(Bb + (32 + fr) * 64 + soff);
            bf16x8 b3 = *(const bf16x8*)(Bb + (48 + fr) * 64 + soff);
            acc[0][0] = __builtin_amdgcn_mfma_f32_16x16x32_bf16(a0, b0, acc[0][0], 0, 0, 0);
            acc[0][1] = __builtin_amdgcn_mfma_f32_16x16x32_bf16(a0, b1, acc[0][1], 0, 0, 0);
            acc[0][2] = __builtin_amdgcn_mfma_f32_16x16x32_bf16(a0, b2, acc[0][2], 0, 0, 0);
            acc[0][3] = __builtin_amdgcn_mfma_f32_16x16x32_bf16(a0, b3, acc[0][3], 0, 0, 0);
            acc[1][0] = __builtin_amdgcn_mfma_f32_16x16x32_bf16(a1, b0, acc[1][0], 0, 0, 0);
            acc[1][1] = __builtin_amdgcn_mfma_f32_16x16x32_bf16(a1, b1, acc[1][1], 0, 0, 0);
            acc[1][2] = __builtin_amdgcn_mfma_f32_16x16x32_bf16(a1, b2, acc[1][2], 0, 0, 0);
            acc[1][3] = __builtin_amdgcn_mfma_f32_16x16x32_bf16(a1, b3, acc[1][3], 0, 0, 0);
        }
        __syncthreads();
        buf ^= 1;
    }

    // epilogue: D col = lane&15 (pixel), row = (lane>>4)*4 + reg (cout)
    const int rbase = (lane >> 4) * 4;
    float* outn = out + (size_t)(n * COUT_ + cout0 + m0) * HW + p0;
    #pragma unroll
    for (int fm = 0; fm < 2; ++fm)
        #pragma unroll
        for (int fn = 0; fn < 4; ++fn)
            #pragma unroll
            for (int r = 0; r < 4; ++r)
                outn[(size_t)(fm * 16 + rbase + r) * HW + fn * 16 + fr] = acc[fm][fn][r];
}

extern "C" void kernel_launch(void* const* d_in, const int* in_sizes, int n_in,
                              void* d_out, int out_size, void* d_ws, size_t ws_size,
                              hipStream_t stream) {
    const float* x      = (const float*)d_in[0];
    const float* weight = (const float*)d_in[1];
    const float* fc_w   = (const float*)d_in[2];
    const float* fc_b   = (const float*)d_in[3];
    float* out = (float*)d_out;

    // workspace layout (~92.9 MB)
    char* ws = (char*)d_ws;
    float* pooled = (float*)ws;                                   // 32 KB
    float* gate   = (float*)(ws + 32 * 1024);                     // 1 KB
    __bf16* wmix  = (__bf16*)(ws + 64 * 1024);                    // 37.75 MB
    __bf16* xTp   = (__bf16*)(ws + 64 * 1024 +
                              (size_t)NBATCH * COUT_ * KTOT * 2); // 55.1 MB

    hipMemsetAsync(pooled, 0, NBATCH * CIN_ * sizeof(float), stream);
    halo_zero_kernel<<<dim3(512), 256, 0, stream>>>(xTp);
    transpose_kernel<<<dim3(49, 4, NBATCH), 256, 0, stream>>>(x, xTp, pooled);
    gate_kernel<<<dim3(1), 256, 0, stream>>>(pooled, fc_w, fc_b, gate);
    mix_kernel<<<dim3(NBATCH * COUT_), 256, 0, stream>>>(weight, gate, wmix);
    conv_kernel<<<dim3(3136), 256, 0, stream>>>(xTp, wmix, out);
}

// Round 5
// 199.474 us; speedup vs baseline: 2.6001x; 1.2663x over previous
//
#include <hip/hip_runtime.h>
#include <hip/hip_bf16.h>

#define E_    8
#define CIN_  256
#define COUT_ 256
#define NK    9
#define KTOT  2304      // CIN*9
#define IMGH  56
#define IMGW  56
#define HW    3136
#define NBATCH 32
#define PADW  58
#define PADHW 3364      // 58*58

typedef __attribute__((ext_vector_type(8))) __bf16 bf16x8;
typedef __attribute__((ext_vector_type(4))) float f32x4;
typedef unsigned int u32;

// async global->LDS, 16B per lane; LDS dest = wave-uniform base + lane*16
__device__ __forceinline__ void gld_lds16(const __bf16* g, __bf16* l) {
    __builtin_amdgcn_global_load_lds(
        (const __attribute__((address_space(1))) void*)(g),
        (__attribute__((address_space(3))) void*)(l), 16, 0, 0);
}

// ---- halo zero: xTp borders = 0 ----
__global__ __launch_bounds__(256) void halo_zero_kernel(__bf16* xTp) {
    const int total = NBATCH * 228 * 128;     // u32 count
    u32* p = (u32*)xTp;
    for (int idx = blockIdx.x * 256 + threadIdx.x; idx < total; idx += gridDim.x * 256) {
        const int n  = idx / (228 * 128);
        const int r  = idx - n * (228 * 128);
        const int hp = r >> 7;
        const int cp = r & 127;
        int px;
        if (hp < 58)       px = hp;
        else if (hp < 116) px = 57 * PADW + (hp - 58);
        else if (hp < 172) px = (hp - 116 + 1) * PADW;
        else               px = (hp - 172 + 1) * PADW + 57;
        p[((size_t)(n * PADHW + px)) * 128 + cp] = 0u;
    }
}

// ---- transpose + pool ----
__global__ __launch_bounds__(256) void transpose_kernel(const float* __restrict__ x,
                                                        __bf16* __restrict__ xTp,
                                                        float* __restrict__ pooled) {
    __shared__ __bf16 t[64][66];
    const int px0 = blockIdx.x * 64;
    const int c0  = blockIdx.y * 64;
    const int n   = blockIdx.z;
    const int tid = threadIdx.x;
    {
        const int px_l = tid & 63;
        const int cb   = (tid >> 6) * 16;
        #pragma unroll
        for (int i = 0; i < 16; ++i) {
            const int cin_l = cb + i;
            t[cin_l][px_l] =
                (__bf16)x[((size_t)(n * CIN_ + c0 + cin_l)) * HW + px0 + px_l];
        }
    }
    __syncthreads();
    {
        const int cin_l = tid & 63;
        const int pb    = (tid >> 6) * 16;
        float s = 0.f;
        #pragma unroll
        for (int i = 0; i < 16; ++i) {
            const int px = px0 + pb + i;
            const int h  = px / IMGW;
            const int w  = px - h * IMGW;
            const __bf16 v = t[cin_l][pb + i];
            s += (float)v;
            xTp[((size_t)(n * PADHW + (h + 1) * PADW + (w + 1))) * CIN_ + c0 + cin_l] = v;
        }
        atomicAdd(&pooled[n * CIN_ + c0 + cin_l], s);
    }
}

// ---- gate ----
__global__ __launch_bounds__(256) void gate_kernel(const float* __restrict__ pooled,
                                                   const float* __restrict__ fc_w,
                                                   const float* __restrict__ fc_b,
                                                   float* __restrict__ gate) {
    const int t = threadIdx.x;
    const int n = t >> 3, e = t & 7;
    const float* pv = pooled + n * CIN_;
    const float* wv = fc_w + e * CIN_;
    float s = 0.f;
    for (int c = 0; c < CIN_; ++c) s += pv[c] * wv[c];
    s = s * (1.0f / HW) + fc_b[e];
    gate[t] = 1.0f / (1.0f + expf(-s));
}

// ---- mix: block = cout; experts in registers; weight read once from HBM ----
__global__ __launch_bounds__(256) void mix_kernel(const float* __restrict__ weight,
                                                  const float* __restrict__ gate,
                                                  __bf16* __restrict__ wmix) {
    __shared__ float wstage[KTOT];            // 9216 B
    __shared__ __bf16 tlds[KTOT];             // 4608 B
    const int cout = blockIdx.x;
    const int tid  = threadIdx.x;
    float wreg[E_][NK];                       // 72 VGPR
    for (int e = 0; e < E_; ++e) {
        const float* wp = weight + (size_t)(e * COUT_ + cout) * KTOT;
        #pragma unroll
        for (int i = 0; i < NK; ++i) wstage[tid + i * 256] = wp[tid + i * 256];
        __syncthreads();
        #pragma unroll
        for (int kk = 0; kk < NK; ++kk) wreg[e][kk] = wstage[tid * NK + kk];
        __syncthreads();
    }
    for (int n = 0; n < NBATCH; ++n) {
        float g[E_];
        #pragma unroll
        for (int e = 0; e < E_; ++e) g[e] = gate[n * E_ + e];
        float acc[NK];
        #pragma unroll
        for (int kk = 0; kk < NK; ++kk) acc[kk] = 0.f;
        #pragma unroll
        for (int e = 0; e < E_; ++e)
            #pragma unroll
            for (int kk = 0; kk < NK; ++kk) acc[kk] += g[e] * wreg[e][kk];
        #pragma unroll
        for (int kk = 0; kk < NK; ++kk) tlds[kk * 256 + tid] = (__bf16)acc[kk];
        __syncthreads();
        u32* dst = (u32*)(wmix + ((size_t)(n * COUT_ + cout)) * KTOT);
        const u32* src = (const u32*)tlds;
        #pragma unroll
        for (int j = 0; j < 4; ++j) dst[tid + j * 256] = src[tid + j * 256];
        if (tid < 128) dst[tid + 1024] = src[tid + 1024];
        __syncthreads();
    }
}

// ---------------- implicit-GEMM conv ----------------
// BM=256 couts x BN=224 pixels, 512 threads, 8 waves as 4M x 2N
// (wave tile 64x112 = 4x7 frags). 36 K-steps of 64, 2-buffer pipeline.
// LDS content at (row, slot s) = global slot s ^ (row&7); source pre-swizzled.
#define BM 256
#define BN 224

__global__ __launch_bounds__(512) void conv_kernel(const __bf16* __restrict__ xTp,
                                                   const __bf16* __restrict__ wmix,
                                                   float* __restrict__ out) {
    __shared__ __attribute__((aligned(16))) __bf16 At[2][BM * 64];  // 2x32 KB
    __shared__ __attribute__((aligned(16))) __bf16 Bt[2][BN * 64];  // 2x28 KB

    // bijective XCD swizzle (448 = 8*56); n-major within XCD for L2 locality
    const int bid = blockIdx.x;
    const int swz = (bid & 7) * 56 + (bid >> 3);
    const int n   = swz / 14;
    const int pt  = swz - n * 14;
    const int p0  = pt * BN;

    const int tid  = threadIdx.x;
    const int lane = tid & 63;
    const int wave = tid >> 6;
    const int lr   = lane >> 3;               // row-within-chunk 0..7
    const int sl   = lane & 7;                // 16B slot within 128B row
    const int swzsl = sl ^ lr;                // pre-swizzled source slot

    const __bf16* wmixn = wmix + (size_t)n * COUT_ * KTOT;
    const __bf16* xTpn  = xTp + (size_t)n * PADHW * CIN_;

    // A staging: chunk j = wave+8i covers cout rows 8j..8j+7
    const __bf16* asrc[4];
    #pragma unroll
    for (int i = 0; i < 4; ++i) {
        const int j = wave + 8 * i;
        asrc[i] = wmixn + (size_t)(8 * j + lr) * KTOT + swzsl * 8;
    }
    // B staging: chunk j = wave+8i (j<28) covers pixel rows 8j..8j+7
    const __bf16* bsrc[4];
    #pragma unroll
    for (int i = 0; i < 4; ++i) {
        int j = wave + 8 * i; if (j > 27) j = 27;   // clamped, never issued
        const int px = p0 + 8 * j + lr;
        const int h  = px / IMGW;
        const int w  = px - h * IMGW;
        bsrc[i] = xTpn + (size_t)(h * PADW + w) * CIN_ + swzsl * 8;
    }

    const f32x4 zero = {0.f, 0.f, 0.f, 0.f};
    f32x4 acc[4][7];
    #pragma unroll
    for (int i = 0; i < 4; ++i)
        #pragma unroll
        for (int j = 0; j < 7; ++j) acc[i][j] = zero;

    const int mbase = (wave >> 1) * 64;
    const int nbase = (wave & 1) * 112;
    const int fr = lane & 15;
    const int kg = lane >> 4;
    const int fswz = fr & 7;

    auto STAGE = [&](int buf, int stepk, int toff) {
        #pragma unroll
        for (int i = 0; i < 4; ++i)
            gld_lds16(asrc[i] + stepk * 64, &At[buf][(wave + 8 * i) * 512]);
        const int boff = toff * 256 + (stepk & 3) * 64;
        #pragma unroll
        for (int i = 0; i < 4; ++i)
            if (wave < 4 || i < 3)
                gld_lds16(bsrc[i] + boff, &Bt[buf][(wave + 8 * i) * 512]);
    };

    auto COMPUTE = [&](const __bf16* Ab, const __bf16* Bb) {
        #pragma unroll
        for (int ks = 0; ks < 2; ++ks) {
            const int soff = ((ks * 4 + kg) ^ fswz) * 8;
            bf16x8 a[4], b[7];
            #pragma unroll
            for (int m = 0; m < 4; ++m)
                a[m] = *(const bf16x8*)(Ab + (mbase + m * 16 + fr) * 64 + soff);
            #pragma unroll
            for (int nn = 0; nn < 7; ++nn)
                b[nn] = *(const bf16x8*)(Bb + (nbase + nn * 16 + fr) * 64 + soff);
            #pragma unroll
            for (int m = 0; m < 4; ++m)
                #pragma unroll
                for (int nn = 0; nn < 7; ++nn)
                    acc[m][nn] = __builtin_amdgcn_mfma_f32_16x16x32_bf16(
                        a[m], b[nn], acc[m][nn], 0, 0, 0);
        }
    };

    STAGE(0, 0, 0);
    __syncthreads();
    for (int khw = 0; khw < 9; ++khw) {
        const int kh  = (khw * 11) >> 5;          // khw/3
        const int kw  = khw - kh * 3;
        const int toff = kh * PADW + kw;
        const int kh2 = ((khw + 1) * 11) >> 5;    // (khw+1)/3 (khw+1<=9 ok)
        const int kw2 = (khw + 1) - kh2 * 3;
        const int toff2 = kh2 * PADW + kw2;
        #pragma unroll
        for (int cb = 0; cb < 4; ++cb) {
            const int buf  = cb & 1;
            const int step = khw * 4 + cb;
            if (step < 35)
                STAGE(buf ^ 1, step + 1, (cb < 3) ? toff : toff2);
            COMPUTE(&At[buf][0], &Bt[buf][0]);
            __syncthreads();
        }
    }

    // epilogue: D col = lane&15 (pixel), row = (lane>>4)*4 + reg (cout)
    const int rbase = kg * 4;
    #pragma unroll
    for (int m = 0; m < 4; ++m)
        #pragma unroll
        for (int nn = 0; nn < 7; ++nn) {
            float* op = out + (size_t)(n * COUT_ + mbase + m * 16 + rbase) * HW
                            + p0 + nbase + nn * 16 + fr;
            #pragma unroll
            for (int r = 0; r < 4; ++r)
                op[(size_t)r * HW] = acc[m][nn][r];
        }
}

extern "C" void kernel_launch(void* const* d_in, const int* in_sizes, int n_in,
                              void* d_out, int out_size, void* d_ws, size_t ws_size,
                              hipStream_t stream) {
    const float* x      = (const float*)d_in[0];
    const float* weight = (const float*)d_in[1];
    const float* fc_w   = (const float*)d_in[2];
    const float* fc_b   = (const float*)d_in[3];
    float* out = (float*)d_out;

    // workspace layout (~92.9 MB)
    char* ws = (char*)d_ws;
    float* pooled = (float*)ws;                                   // 32 KB
    float* gate   = (float*)(ws + 32 * 1024);                     // 1 KB
    __bf16* wmix  = (__bf16*)(ws + 64 * 1024);                    // 37.75 MB
    __bf16* xTp   = (__bf16*)(ws + 64 * 1024 +
                              (size_t)NBATCH * COUT_ * KTOT * 2); // 55.1 MB

    hipMemsetAsync(pooled, 0, NBATCH * CIN_ * sizeof(float), stream);
    halo_zero_kernel<<<dim3(512), 256, 0, stream>>>(xTp);
    transpose_kernel<<<dim3(49, 4, NBATCH), 256, 0, stream>>>(x, xTp, pooled);
    gate_kernel<<<dim3(1), 256, 0, stream>>>(pooled, fc_w, fc_b, gate);
    mix_kernel<<<dim3(COUT_), 256, 0, stream>>>(weight, gate, wmix);
    conv_kernel<<<dim3(448), 512, 0, stream>>>(xTp, wmix, out);
}